// Round 4
// baseline (2531.808 us; speedup 1.0000x reference)
//
#include <hip/hip_runtime.h>
#include <math.h>

#define NN 1000000
#define FF 5
#define EE 32000000
#define BBITS 10
#define BWIDTH 1024
#define NBUCK 977            /* ((NN-1)>>BBITS)+1 */
#define GBITS 16             /* src-group = src>>16 -> 16 groups of 64K nodes */
#define NG 16
#define NBIN (NBUCK * NG)    /* 15632 composite bins */
#define NBLK 256             /* edge-slice blocks for hist/scatter */
#define SLICE (EE / NBLK)    /* 125000 exactly */

typedef unsigned u32;
typedef u32 u32x4 __attribute__((ext_vector_type(4)));
typedef int i32x4 __attribute__((ext_vector_type(4)));

// ============================ FAST PATH ============================

// Pass A: per-slice-block histogram over (dstBucket, srcGroup) bins.
__global__ __launch_bounds__(1024) void k_hist(const int* __restrict__ ei,
                                               u32* __restrict__ blockHist,
                                               u32* __restrict__ binTotals) {
    __shared__ u32 h[NBIN];
    int t = threadIdx.x, blk = blockIdx.x;
    for (int i = t; i < NBIN; i += 1024) h[i] = 0u;
    __syncthreads();
    const i32x4* srcs = (const i32x4*)(ei + (size_t)blk * SLICE);
    const i32x4* dsts = (const i32x4*)(ei + EE + (size_t)blk * SLICE);
    for (int i = t; i < SLICE / 4; i += 1024) {
        i32x4 s4 = __builtin_nontemporal_load(srcs + i);
        i32x4 d4 = __builtin_nontemporal_load(dsts + i);
        atomicAdd(&h[(((u32)d4.x) >> BBITS) * NG + (((u32)s4.x) >> GBITS)], 1u);
        atomicAdd(&h[(((u32)d4.y) >> BBITS) * NG + (((u32)s4.y) >> GBITS)], 1u);
        atomicAdd(&h[(((u32)d4.z) >> BBITS) * NG + (((u32)s4.z) >> GBITS)], 1u);
        atomicAdd(&h[(((u32)d4.w) >> BBITS) * NG + (((u32)s4.w) >> GBITS)], 1u);
    }
    __syncthreads();
    for (int i = t; i < NBIN; i += 1024) {
        u32 c = h[i];
        blockHist[(size_t)i * NBLK + blk] = c;
        if (c) atomicAdd(&binTotals[i], c);
    }
}

// Pass B1: bucket totals (padded to 8) -> bucket bases; bin bases within bucket.
__global__ __launch_bounds__(1024) void k_base(const u32* __restrict__ binTotals,
                                               u32* __restrict__ binBase,
                                               u32* __restrict__ bucketBase,
                                               u32* __restrict__ bucketTotals) {
    __shared__ u32 s[1024];
    int t = threadIdx.x;
    u32 bt[NG];
    u32 tot = 0;
    if (t < NBUCK) {
#pragma unroll
        for (int g = 0; g < NG; g++) { bt[g] = binTotals[t * NG + g]; tot += bt[g]; }
    }
    u32 padded = (t < NBUCK) ? ((tot + 7u) & ~7u) : 0u;
    s[t] = padded;
    __syncthreads();
    for (int off = 1; off < 1024; off <<= 1) {
        u32 add = (t >= off) ? s[t - off] : 0u;
        __syncthreads();
        s[t] += add;
        __syncthreads();
    }
    if (t < NBUCK) {
        u32 b0 = s[t] - padded;               // exclusive padded base
        bucketBase[t] = b0;
        bucketTotals[t] = tot;
        u32 run = b0;
#pragma unroll
        for (int g = 0; g < NG; g++) { binBase[t * NG + g] = run; run += bt[g]; }
    }
}

// Pass B2: per-bin scan across slice-blocks, in place: blockHist -> write offsets.
__global__ __launch_bounds__(NBLK) void k_off(u32* __restrict__ blockHist,
                                              const u32* __restrict__ binBase) {
    __shared__ u32 s[NBLK];
    size_t base = (size_t)blockIdx.x * NBLK;
    int t = threadIdx.x;
    u32 v = blockHist[base + t];
    s[t] = v;
    __syncthreads();
    for (int off = 1; off < NBLK; off <<= 1) {
        u32 a = (t >= off) ? s[t - off] : 0u;
        __syncthreads();
        s[t] += a;
        __syncthreads();
    }
    blockHist[base + t] = binBase[blockIdx.x] + s[t] - v;
}

// Pass C: scatter edges into (bucket-major, src-group-minor) binned array.
__global__ __launch_bounds__(1024) void k_scatter(const int* __restrict__ ei,
                                                  const u32* __restrict__ blockHist,
                                                  u32* __restrict__ binned) {
    __shared__ u32 cnt[NBIN];
    int t = threadIdx.x, blk = blockIdx.x;
    for (int i = t; i < NBIN; i += 1024)
        cnt[i] = blockHist[(size_t)i * NBLK + blk];
    __syncthreads();
    const i32x4* srcs = (const i32x4*)(ei + (size_t)blk * SLICE);
    const i32x4* dsts = (const i32x4*)(ei + EE + (size_t)blk * SLICE);
    for (int i = t; i < SLICE / 4; i += 1024) {
        i32x4 s4 = __builtin_nontemporal_load(srcs + i);
        i32x4 d4 = __builtin_nontemporal_load(dsts + i);
#pragma unroll
        for (int j = 0; j < 4; j++) {
            u32 s = (u32)((j == 0) ? s4.x : (j == 1) ? s4.y : (j == 2) ? s4.z : s4.w);
            u32 d = (u32)((j == 0) ? d4.x : (j == 1) ? d4.y : (j == 2) ? d4.z : d4.w);
            u32 pos = atomicAdd(&cnt[(d >> BBITS) * NG + (s >> GBITS)], 1u);
            binned[pos] = (s << BBITS) | (d & (BWIDTH - 1));
        }
    }
}

// Pad each bucket segment to a multiple of 8 with sentinel edges (src=NN -> zero row).
__global__ __launch_bounds__(1024) void k_pad(const u32* __restrict__ bucketTotals,
                                              const u32* __restrict__ bucketBase,
                                              u32* __restrict__ binned) {
    int t = threadIdx.x;
    if (t >= NBUCK) return;
    u32 len = bucketTotals[t];
    u32 st = bucketBase[t] + len;
    u32 en = bucketBase[t] + ((len + 7u) & ~7u);
    for (u32 u = st; u < en; u++) binned[u] = ((u32)NN) << BBITS;
}

// Fused: degree -> dis -> y = (x@W1)*dis. y rows: [o0..o4, dis, 0, 0]; row NN zero.
__global__ __launch_bounds__(1024) void k_disy(const u32* __restrict__ binned,
                                               const u32* __restrict__ bucketBase,
                                               const u32* __restrict__ bucketTotals,
                                               const float* __restrict__ x,
                                               const float* __restrict__ W,
                                               float* __restrict__ y) {
    __shared__ u32 c[BWIDTH];
    int t = threadIdx.x, b = blockIdx.x;
    c[t] = 0u;
    __syncthreads();
    u32 start = bucketBase[b], len = bucketTotals[b], lenp = (len + 7u) & ~7u;
    for (u32 i = (u32)t * 8u; i < lenp; i += 8192u) {
        const u32x4* bp = (const u32x4*)(binned + start + i);
        u32x4 a = __builtin_nontemporal_load(bp);
        u32x4 d = __builtin_nontemporal_load(bp + 1);
        u32 p[8] = {a.x, a.y, a.z, a.w, d.x, d.y, d.z, d.w};
#pragma unroll
        for (int j = 0; j < 8; j++)
            if ((p[j] >> BBITS) != (u32)NN)
                atomicAdd(&c[p[j] & (BWIDTH - 1)], 1u);
    }
    __syncthreads();
    int node = (b << BBITS) + t;
    if (node > NN) return;
    float4* dst = (float4*)(y + (size_t)node * 8);
    if (node == NN) {
        dst[0] = make_float4(0.f, 0.f, 0.f, 0.f);
        dst[1] = make_float4(0.f, 0.f, 0.f, 0.f);
        return;
    }
    float d = rsqrtf((float)(c[t] + 1u));
    float xi[FF];
#pragma unroll
    for (int f = 0; f < FF; f++) xi[f] = x[(size_t)node * FF + f];
    float o[FF];
#pragma unroll
    for (int q = 0; q < FF; q++) {
        float acc = 0.f;
#pragma unroll
        for (int k = 0; k < FF; k++) acc += xi[k] * W[k * FF + q];
        o[q] = acc * d;
    }
    dst[0] = make_float4(o[0], o[1], o[2], o[3]);
    dst[1] = make_float4(o[4], d, 0.f, 0.f);
}

// layer-1 aggregate + fused epilogue. Persistent grid: block handles b, b+512.
__global__ __launch_bounds__(1024) void k_agg1(const u32* __restrict__ binned,
                                               const u32* __restrict__ bucketBase,
                                               const u32* __restrict__ bucketTotals,
                                               const float* __restrict__ y,
                                               const float* __restrict__ b1,
                                               const float* __restrict__ W2,
                                               float* __restrict__ y2) {
    __shared__ float acc[BWIDTH * FF];
    int t = threadIdx.x;
    for (int b = blockIdx.x; b < NBUCK; b += (int)gridDim.x) {
#pragma unroll
        for (int i = 0; i < FF; i++) acc[i * 1024 + t] = 0.f;
        __syncthreads();
        u32 start = bucketBase[b], len = bucketTotals[b], lenp = (len + 7u) & ~7u;
        for (u32 i = (u32)t * 8u; i < lenp; i += 8192u) {
            const u32x4* bp = (const u32x4*)(binned + start + i);
            u32x4 qa = __builtin_nontemporal_load(bp);
            u32x4 qb = __builtin_nontemporal_load(bp + 1);
            u32 p[8] = {qa.x, qa.y, qa.z, qa.w, qb.x, qb.y, qb.z, qb.w};
            float4 v4[8]; float v5[8];
#pragma unroll
            for (int j = 0; j < 8; j++) {
                const float* yr = y + (size_t)(p[j] >> BBITS) * 8;
                v4[j] = *(const float4*)yr;
                v5[j] = yr[4];
            }
#pragma unroll
            for (int j = 0; j < 8; j++) {
                float* a = acc + (p[j] & (BWIDTH - 1)) * FF;
                atomicAdd(a + 0, v4[j].x);
                atomicAdd(a + 1, v4[j].y);
                atomicAdd(a + 2, v4[j].z);
                atomicAdd(a + 3, v4[j].w);
                atomicAdd(a + 4, v5[j]);
            }
        }
        __syncthreads();
        int node = (b << BBITS) + t;
        if (node <= NN) {
            float4* dst = (float4*)(y2 + (size_t)node * 8);
            if (node == NN) {
                dst[0] = make_float4(0.f, 0.f, 0.f, 0.f);
                dst[1] = make_float4(0.f, 0.f, 0.f, 0.f);
            } else {
                const float* yr = y + (size_t)node * 8;
                float4 lo = *(const float4*)yr;
                float4 hi = *(const float4*)(yr + 4);
                float d = hi.y;                       // dis in slot 5
                float self[FF] = {lo.x, lo.y, lo.z, lo.w, hi.x};
                float h[FF];
#pragma unroll
                for (int f = 0; f < FF; f++)
                    h[f] = fmaxf((acc[t * FF + f] + self[f]) * d + b1[f], 0.f);
                float o[FF];
#pragma unroll
                for (int q = 0; q < FF; q++) {
                    float s = 0.f;
#pragma unroll
                    for (int k = 0; k < FF; k++) s += h[k] * W2[k * FF + q];
                    o[q] = s * d;
                }
                dst[0] = make_float4(o[0], o[1], o[2], o[3]);
                dst[1] = make_float4(o[4], d, 0.f, 0.f);
            }
        }
        __syncthreads();   // epilogue done before next bucket re-zeroes acc
    }
}

// layer-2 aggregate + fused head. Persistent grid.
__global__ __launch_bounds__(1024) void k_agg2(const u32* __restrict__ binned,
                                               const u32* __restrict__ bucketBase,
                                               const u32* __restrict__ bucketTotals,
                                               const float* __restrict__ y2,
                                               const float* __restrict__ b2,
                                               const float* __restrict__ Wl,
                                               const float* __restrict__ bl,
                                               float* __restrict__ out) {
    __shared__ float acc[BWIDTH * FF];
    int t = threadIdx.x;
    for (int b = blockIdx.x; b < NBUCK; b += (int)gridDim.x) {
#pragma unroll
        for (int i = 0; i < FF; i++) acc[i * 1024 + t] = 0.f;
        __syncthreads();
        u32 start = bucketBase[b], len = bucketTotals[b], lenp = (len + 7u) & ~7u;
        for (u32 i = (u32)t * 8u; i < lenp; i += 8192u) {
            const u32x4* bp = (const u32x4*)(binned + start + i);
            u32x4 qa = __builtin_nontemporal_load(bp);
            u32x4 qb = __builtin_nontemporal_load(bp + 1);
            u32 p[8] = {qa.x, qa.y, qa.z, qa.w, qb.x, qb.y, qb.z, qb.w};
            float4 v4[8]; float v5[8];
#pragma unroll
            for (int j = 0; j < 8; j++) {
                const float* yr = y2 + (size_t)(p[j] >> BBITS) * 8;
                v4[j] = *(const float4*)yr;
                v5[j] = yr[4];
            }
#pragma unroll
            for (int j = 0; j < 8; j++) {
                float* a = acc + (p[j] & (BWIDTH - 1)) * FF;
                atomicAdd(a + 0, v4[j].x);
                atomicAdd(a + 1, v4[j].y);
                atomicAdd(a + 2, v4[j].z);
                atomicAdd(a + 3, v4[j].w);
                atomicAdd(a + 4, v5[j]);
            }
        }
        __syncthreads();
        int node = (b << BBITS) + t;
        if (node < NN) {
            const float* yr = y2 + (size_t)node * 8;
            float4 lo = *(const float4*)yr;
            float4 hi = *(const float4*)(yr + 4);
            float d = hi.y;
            float self[FF] = {lo.x, lo.y, lo.z, lo.w, hi.x};
            float v = bl[0];
#pragma unroll
            for (int f = 0; f < FF; f++)
                v += fmaxf((acc[t * FF + f] + self[f]) * d + b2[f], 0.f) * Wl[f];
            out[node] = v;
        }
        __syncthreads();
    }
}

// ===================== FALLBACK (round-1 atomic path) =====================

__global__ void k_deg(const int* __restrict__ ei, int E, unsigned int* __restrict__ deg) {
    int t = blockIdx.x * blockDim.x + threadIdx.x;
    int stride = gridDim.x * blockDim.x;
    for (int e = t; e < E; e += stride) atomicAdd(&deg[ei[E + e]], 1u);
}
__global__ void k_dis(const unsigned int* __restrict__ deg, float* __restrict__ dis) {
    int i = blockIdx.x * blockDim.x + threadIdx.x;
    if (i < NN) dis[i] = rsqrtf((float)(deg[i] + 1u));
}
__global__ void k_y1(const float* __restrict__ x, const float* __restrict__ dis,
                     const float* __restrict__ W, float* __restrict__ y, float* __restrict__ z) {
    int i = blockIdx.x * blockDim.x + threadIdx.x;
    if (i >= NN) return;
    float xi[FF];
#pragma unroll
    for (int f = 0; f < FF; f++) xi[f] = x[i * FF + f];
    float d = dis[i];
#pragma unroll
    for (int o = 0; o < FF; o++) {
        float acc = 0.f;
#pragma unroll
        for (int k = 0; k < FF; k++) acc += xi[k] * W[k * FF + o];
        acc *= d;
        y[i * FF + o] = acc;
        z[i * FF + o] = acc;
    }
}
__global__ void k_edge(const int* __restrict__ ei, int E,
                       const float* __restrict__ y, float* __restrict__ z) {
    int t = blockIdx.x * blockDim.x + threadIdx.x;
    int stride = gridDim.x * blockDim.x;
    for (int e = t; e < E; e += stride) {
        int s = ei[e], d = ei[E + e];
        const float* ys = y + (size_t)s * FF;
        float* zd = z + (size_t)d * FF;
#pragma unroll
        for (int f = 0; f < FF; f++) atomicAdd(&zd[f], ys[f]);
    }
}
__global__ void k_mid(const float* __restrict__ z1, const float* __restrict__ dis,
                      const float* __restrict__ b1, const float* __restrict__ W2,
                      float* __restrict__ y2, float* __restrict__ z2) {
    int i = blockIdx.x * blockDim.x + threadIdx.x;
    if (i >= NN) return;
    float d = dis[i];
    float h[FF];
#pragma unroll
    for (int f = 0; f < FF; f++) h[f] = fmaxf(z1[i * FF + f] * d + b1[f], 0.f);
#pragma unroll
    for (int o = 0; o < FF; o++) {
        float acc = 0.f;
#pragma unroll
        for (int k = 0; k < FF; k++) acc += h[k] * W2[k * FF + o];
        acc *= d;
        y2[i * FF + o] = acc;
        z2[i * FF + o] = acc;
    }
}
__global__ void k_final(const float* __restrict__ z2, const float* __restrict__ dis,
                        const float* __restrict__ b2, const float* __restrict__ Wl,
                        const float* __restrict__ bl, float* __restrict__ out) {
    int i = blockIdx.x * blockDim.x + threadIdx.x;
    if (i >= NN) return;
    float d = dis[i];
    float acc = bl[0];
#pragma unroll
    for (int f = 0; f < FF; f++)
        acc += fmaxf(z2[i * FF + f] * d + b2[f], 0.f) * Wl[f];
    out[i] = acc;
}

// ================================ launch ================================

extern "C" void kernel_launch(void* const* d_in, const int* in_sizes, int n_in,
                              void* d_out, int out_size, void* d_ws, size_t ws_size,
                              hipStream_t stream) {
    const float* x  = (const float*)d_in[0];
    const int*   ei = (const int*)d_in[1];
    const float* W1 = (const float*)d_in[2];
    const float* b1 = (const float*)d_in[3];
    const float* W2 = (const float*)d_in[4];
    const float* b2 = (const float*)d_in[5];
    const float* Wl = (const float*)d_in[6];
    const float* bl = (const float*)d_in[7];
    float* out = (float*)d_out;
    const int E = in_sizes[1] / 2;

    char* ws = (char*)d_ws;
    const size_t REQUIRED = 202ull << 20;

    if (E == EE && ws_size >= REQUIRED) {
        // layout: binTotals@0(64K), binBase@64K, bucketBase@128K, bucketTot@132K,
        // blockHist@1M (15.3MiB), y@17M (30.6MiB), y2@48M, binned@79M (122.1MiB)
        u32* binTotals    = (u32*)(ws);
        u32* binBase      = (u32*)(ws + (64 << 10));
        u32* bucketBase   = (u32*)(ws + (128 << 10));
        u32* bucketTotals = (u32*)(ws + (132 << 10));
        u32* blockHist    = (u32*)(ws + (1ull << 20));
        float* y          = (float*)(ws + (17ull << 20));
        float* y2         = (float*)(ws + (48ull << 20));
        u32* binned       = (u32*)(ws + (79ull << 20));

        hipMemsetAsync(binTotals, 0, NBIN * sizeof(u32), stream);

        k_hist   <<<NBLK, 1024, 0, stream>>>(ei, blockHist, binTotals);
        k_base   <<<1, 1024, 0, stream>>>(binTotals, binBase, bucketBase, bucketTotals);
        k_off    <<<NBIN, NBLK, 0, stream>>>(blockHist, binBase);
        k_scatter<<<NBLK, 1024, 0, stream>>>(ei, blockHist, binned);
        k_pad    <<<1, 1024, 0, stream>>>(bucketTotals, bucketBase, binned);
        k_disy   <<<NBUCK, 1024, 0, stream>>>(binned, bucketBase, bucketTotals, x, W1, y);
        k_agg1   <<<512, 1024, 0, stream>>>(binned, bucketBase, bucketTotals, y, b1, W2, y2);
        k_agg2   <<<512, 1024, 0, stream>>>(binned, bucketBase, bucketTotals, y2, b2, Wl, bl, out);
    } else {
        // -------- fallback: round-1 global-atomic path (needs 68 MB) --------
        unsigned int* deg = (unsigned int*)(ws);
        float* dis = (float*)(ws + (size_t)4 * 1024 * 1024);
        float* A   = (float*)(ws + (size_t)8 * 1024 * 1024);
        float* B   = (float*)(ws + (size_t)28 * 1024 * 1024);
        float* C   = (float*)(ws + (size_t)48 * 1024 * 1024);

        hipMemsetAsync(deg, 0, (size_t)NN * sizeof(unsigned int), stream);

        const int ET = 256, EB = 2048;
        const int NT = 256, NB = (NN + NT - 1) / NT;
        k_deg  <<<EB, ET, 0, stream>>>(ei, E, deg);
        k_dis  <<<NB, NT, 0, stream>>>(deg, dis);
        k_y1   <<<NB, NT, 0, stream>>>(x, dis, W1, A, B);
        k_edge <<<EB, ET, 0, stream>>>(ei, E, A, B);
        k_mid  <<<NB, NT, 0, stream>>>(B, dis, b1, W2, A, C);
        k_edge <<<EB, ET, 0, stream>>>(ei, E, A, C);
        k_final<<<NB, NT, 0, stream>>>(C, dis, b2, Wl, bl, out);
    }
}

// Round 5
// 2171.029 us; speedup vs baseline: 1.1662x; 1.1662x over previous
//
#include <hip/hip_runtime.h>
#include <math.h>

#define NN 1000000
#define FF 5
#define EE 32000000
#define BBITS 10
#define BWIDTH 1024
#define NBUCK 977            /* ((NN-1)>>BBITS)+1 */
#define NBLK 512             /* edge-slice blocks for hist/scatter */
#define SLICE (EE / NBLK)    /* 62500 exactly */

typedef unsigned u32;
typedef u32 u32x4 __attribute__((ext_vector_type(4)));
typedef int i32x4 __attribute__((ext_vector_type(4)));

// ---- 16B row codec: 4 x f24 (rounded) + 1 x f32 exact ----
__device__ __forceinline__ u32 rnd24(float v) {
    return (__float_as_uint(v) + 0x80u) >> 8;   // round-to-nearest 24-bit float
}
__device__ __forceinline__ uint4 pack_row(float o0, float o1, float o2, float o3, float o4) {
    u32 t0 = rnd24(o0), t1 = rnd24(o1), t2 = rnd24(o2), t3 = rnd24(o3);
    uint4 r;
    r.x = t0 | (t1 << 24);
    r.y = (t1 >> 8) | (t2 << 16);
    r.z = (t2 >> 16) | (t3 << 8);
    r.w = __float_as_uint(o4);
    return r;
}
__device__ __forceinline__ void unpack_row(uint4 r, float* f) {
    f[0] = __uint_as_float(r.x << 8);
    f[1] = __uint_as_float(((r.x >> 24) << 8) | (r.y << 16));
    f[2] = __uint_as_float(((r.y >> 16) << 8) | (r.z << 24));
    f[3] = __uint_as_float(r.z & 0xFFFFFF00u);
    f[4] = __uint_as_float(r.w);
}

// ============================ FAST PATH ============================

// Pass A: per-slice-block histogram of dst buckets.
__global__ __launch_bounds__(1024) void k_hist(const int* __restrict__ ei,
                                               u32* __restrict__ blockHist,
                                               u32* __restrict__ totals) {
    __shared__ u32 h[NBUCK];
    int t = threadIdx.x, blk = blockIdx.x;
    for (int i = t; i < NBUCK; i += 1024) h[i] = 0u;
    __syncthreads();
    const i32x4* dsts = (const i32x4*)(ei + EE + (size_t)blk * SLICE);
    for (int i = t; i < SLICE / 4; i += 1024) {
        i32x4 d = __builtin_nontemporal_load(dsts + i);
        atomicAdd(&h[((u32)d.x) >> BBITS], 1u);
        atomicAdd(&h[((u32)d.y) >> BBITS], 1u);
        atomicAdd(&h[((u32)d.z) >> BBITS], 1u);
        atomicAdd(&h[((u32)d.w) >> BBITS], 1u);
    }
    __syncthreads();
    for (int i = t; i < NBUCK; i += 1024) {
        u32 c = h[i];
        blockHist[(size_t)i * NBLK + blk] = c;   // bucket-major
        if (c) atomicAdd(&totals[i], c);
    }
}

// Pass B1: exclusive scan over PADDED (to 8) bucket totals -> bucket bases.
__global__ __launch_bounds__(1024) void k_base(const u32* __restrict__ totals,
                                               u32* __restrict__ base) {
    __shared__ u32 s[1024];
    int t = threadIdx.x;
    u32 v = (t < NBUCK) ? ((totals[t] + 7u) & ~7u) : 0u;
    s[t] = v;
    __syncthreads();
    for (int off = 1; off < 1024; off <<= 1) {
        u32 add = (t >= off) ? s[t - off] : 0u;
        __syncthreads();
        s[t] += add;
        __syncthreads();
    }
    if (t < NBUCK) base[t] = s[t] - v;
}

// Pass B2: per-bucket scan across slice-blocks, in place -> absolute offsets.
__global__ __launch_bounds__(NBLK) void k_off(u32* __restrict__ blockHist,
                                              const u32* __restrict__ base) {
    __shared__ u32 s[NBLK];
    size_t bb = (size_t)blockIdx.x * NBLK;
    int t = threadIdx.x;
    u32 v = blockHist[bb + t];
    s[t] = v;
    __syncthreads();
    for (int off = 1; off < NBLK; off <<= 1) {
        u32 a = (t >= off) ? s[t - off] : 0u;
        __syncthreads();
        s[t] += a;
        __syncthreads();
    }
    blockHist[bb + t] = base[blockIdx.x] + s[t] - v;
}

// Pass C: scatter edges into bucket-contiguous binned array (plain writes).
__global__ __launch_bounds__(1024) void k_scatter(const int* __restrict__ ei,
                                                  const u32* __restrict__ blockHist,
                                                  u32* __restrict__ binned) {
    __shared__ u32 cnt[NBUCK];
    int t = threadIdx.x, blk = blockIdx.x;
    for (int i = t; i < NBUCK; i += 1024)
        cnt[i] = blockHist[(size_t)i * NBLK + blk];
    __syncthreads();
    const i32x4* srcs = (const i32x4*)(ei + (size_t)blk * SLICE);
    const i32x4* dsts = (const i32x4*)(ei + EE + (size_t)blk * SLICE);
    for (int i = t; i < SLICE / 4; i += 1024) {
        i32x4 s4 = __builtin_nontemporal_load(srcs + i);
        i32x4 d4 = __builtin_nontemporal_load(dsts + i);
#pragma unroll
        for (int j = 0; j < 4; j++) {
            u32 s = (u32)((j == 0) ? s4.x : (j == 1) ? s4.y : (j == 2) ? s4.z : s4.w);
            u32 d = (u32)((j == 0) ? d4.x : (j == 1) ? d4.y : (j == 2) ? d4.z : d4.w);
            u32 pos = atomicAdd(&cnt[d >> BBITS], 1u);
            binned[pos] = (s << BBITS) | (d & (BWIDTH - 1));
        }
    }
}

// Pad each bucket segment to a multiple of 8 with sentinel edges (src=NN -> zero row).
__global__ __launch_bounds__(1024) void k_pad(const u32* __restrict__ totals,
                                              const u32* __restrict__ base,
                                              u32* __restrict__ binned) {
    int t = threadIdx.x;
    if (t >= NBUCK) return;
    u32 len = totals[t];
    u32 st = base[t] + len;
    u32 en = base[t] + ((len + 7u) & ~7u);
    for (u32 u = st; u < en; u++) binned[u] = ((u32)NN) << BBITS;
}

// Fused: degree -> dis -> packed y16 = pack((x@W1)*dis). Row NN is zero sentinel.
__global__ __launch_bounds__(1024) void k_disy(const u32* __restrict__ binned,
                                               const u32* __restrict__ base,
                                               const u32* __restrict__ totals,
                                               const float* __restrict__ x,
                                               const float* __restrict__ W,
                                               float* __restrict__ dis,
                                               uint4* __restrict__ y16) {
    __shared__ u32 c[BWIDTH];
    int t = threadIdx.x, b = blockIdx.x;
    c[t] = 0u;
    __syncthreads();
    u32 start = base[b], len = totals[b], lenp = (len + 7u) & ~7u;
    for (u32 i = (u32)t * 8u; i < lenp; i += 8192u) {
        const u32x4* bp = (const u32x4*)(binned + start + i);
        u32x4 a = __builtin_nontemporal_load(bp);
        u32x4 d = __builtin_nontemporal_load(bp + 1);
        u32 p[8] = {a.x, a.y, a.z, a.w, d.x, d.y, d.z, d.w};
#pragma unroll
        for (int j = 0; j < 8; j++)
            if ((p[j] >> BBITS) != (u32)NN)
                atomicAdd(&c[p[j] & (BWIDTH - 1)], 1u);
    }
    __syncthreads();
    int node = (b << BBITS) + t;
    if (node > NN) return;
    if (node == NN) {
        y16[node] = make_uint4(0u, 0u, 0u, 0u);
        return;
    }
    float d = rsqrtf((float)(c[t] + 1u));
    dis[node] = d;
    float xi[FF];
#pragma unroll
    for (int f = 0; f < FF; f++) xi[f] = x[(size_t)node * FF + f];
    float o[FF];
#pragma unroll
    for (int q = 0; q < FF; q++) {
        float acc = 0.f;
#pragma unroll
        for (int k = 0; k < FF; k++) acc += xi[k] * W[k * FF + q];
        o[q] = acc * d;
    }
    y16[node] = pack_row(o[0], o[1], o[2], o[3], o[4]);
}

// layer-1 aggregate + fused epilogue -> packed y2.
__global__ __launch_bounds__(1024) void k_agg1(const u32* __restrict__ binned,
                                               const u32* __restrict__ base,
                                               const u32* __restrict__ totals,
                                               const uint4* __restrict__ y16,
                                               const float* __restrict__ dis,
                                               const float* __restrict__ b1,
                                               const float* __restrict__ W2,
                                               uint4* __restrict__ y2) {
    __shared__ float acc[BWIDTH * FF];
    int t = threadIdx.x, b = blockIdx.x;
#pragma unroll
    for (int i = 0; i < FF; i++) acc[i * 1024 + t] = 0.f;
    __syncthreads();
    u32 start = base[b], len = totals[b], lenp = (len + 7u) & ~7u;
    for (u32 i = (u32)t * 8u; i < lenp; i += 8192u) {
        const u32x4* bp = (const u32x4*)(binned + start + i);
        u32x4 qa = __builtin_nontemporal_load(bp);
        u32x4 qb = __builtin_nontemporal_load(bp + 1);
        u32 p[8] = {qa.x, qa.y, qa.z, qa.w, qb.x, qb.y, qb.z, qb.w};
        uint4 r[8];
#pragma unroll
        for (int j = 0; j < 8; j++)        // ONE 16B gather per edge
            r[j] = y16[p[j] >> BBITS];
#pragma unroll
        for (int j = 0; j < 8; j++) {
            float f[FF];
            unpack_row(r[j], f);
            float* a = acc + (p[j] & (BWIDTH - 1)) * FF;
            atomicAdd(a + 0, f[0]);
            atomicAdd(a + 1, f[1]);
            atomicAdd(a + 2, f[2]);
            atomicAdd(a + 3, f[3]);
            atomicAdd(a + 4, f[4]);
        }
    }
    __syncthreads();
    int node = (b << BBITS) + t;
    if (node > NN) return;
    if (node == NN) {
        y2[node] = make_uint4(0u, 0u, 0u, 0u);
        return;
    }
    float self[FF];
    unpack_row(y16[node], self);
    float d = dis[node];
    float h[FF];
#pragma unroll
    for (int f = 0; f < FF; f++)
        h[f] = fmaxf((acc[t * FF + f] + self[f]) * d + b1[f], 0.f);
    float o[FF];
#pragma unroll
    for (int q = 0; q < FF; q++) {
        float s = 0.f;
#pragma unroll
        for (int k = 0; k < FF; k++) s += h[k] * W2[k * FF + q];
        o[q] = s * d;
    }
    y2[node] = pack_row(o[0], o[1], o[2], o[3], o[4]);
}

// layer-2 aggregate + fused head -> out.
__global__ __launch_bounds__(1024) void k_agg2(const u32* __restrict__ binned,
                                               const u32* __restrict__ base,
                                               const u32* __restrict__ totals,
                                               const uint4* __restrict__ y2,
                                               const float* __restrict__ dis,
                                               const float* __restrict__ b2,
                                               const float* __restrict__ Wl,
                                               const float* __restrict__ bl,
                                               float* __restrict__ out) {
    __shared__ float acc[BWIDTH * FF];
    int t = threadIdx.x, b = blockIdx.x;
#pragma unroll
    for (int i = 0; i < FF; i++) acc[i * 1024 + t] = 0.f;
    __syncthreads();
    u32 start = base[b], len = totals[b], lenp = (len + 7u) & ~7u;
    for (u32 i = (u32)t * 8u; i < lenp; i += 8192u) {
        const u32x4* bp = (const u32x4*)(binned + start + i);
        u32x4 qa = __builtin_nontemporal_load(bp);
        u32x4 qb = __builtin_nontemporal_load(bp + 1);
        u32 p[8] = {qa.x, qa.y, qa.z, qa.w, qb.x, qb.y, qb.z, qb.w};
        uint4 r[8];
#pragma unroll
        for (int j = 0; j < 8; j++)
            r[j] = y2[p[j] >> BBITS];
#pragma unroll
        for (int j = 0; j < 8; j++) {
            float f[FF];
            unpack_row(r[j], f);
            float* a = acc + (p[j] & (BWIDTH - 1)) * FF;
            atomicAdd(a + 0, f[0]);
            atomicAdd(a + 1, f[1]);
            atomicAdd(a + 2, f[2]);
            atomicAdd(a + 3, f[3]);
            atomicAdd(a + 4, f[4]);
        }
    }
    __syncthreads();
    int node = (b << BBITS) + t;
    if (node >= NN) return;
    float self[FF];
    unpack_row(y2[node], self);
    float d = dis[node];
    float v = bl[0];
#pragma unroll
    for (int f = 0; f < FF; f++)
        v += fmaxf((acc[t * FF + f] + self[f]) * d + b2[f], 0.f) * Wl[f];
    out[node] = v;
}

// ===================== FALLBACK (round-1 atomic path) =====================

__global__ void k_deg(const int* __restrict__ ei, int E, unsigned int* __restrict__ deg) {
    int t = blockIdx.x * blockDim.x + threadIdx.x;
    int stride = gridDim.x * blockDim.x;
    for (int e = t; e < E; e += stride) atomicAdd(&deg[ei[E + e]], 1u);
}
__global__ void k_dis(const unsigned int* __restrict__ deg, float* __restrict__ dis) {
    int i = blockIdx.x * blockDim.x + threadIdx.x;
    if (i < NN) dis[i] = rsqrtf((float)(deg[i] + 1u));
}
__global__ void k_y1(const float* __restrict__ x, const float* __restrict__ dis,
                     const float* __restrict__ W, float* __restrict__ y, float* __restrict__ z) {
    int i = blockIdx.x * blockDim.x + threadIdx.x;
    if (i >= NN) return;
    float xi[FF];
#pragma unroll
    for (int f = 0; f < FF; f++) xi[f] = x[i * FF + f];
    float d = dis[i];
#pragma unroll
    for (int o = 0; o < FF; o++) {
        float acc = 0.f;
#pragma unroll
        for (int k = 0; k < FF; k++) acc += xi[k] * W[k * FF + o];
        acc *= d;
        y[i * FF + o] = acc;
        z[i * FF + o] = acc;
    }
}
__global__ void k_edge(const int* __restrict__ ei, int E,
                       const float* __restrict__ y, float* __restrict__ z) {
    int t = blockIdx.x * blockDim.x + threadIdx.x;
    int stride = gridDim.x * blockDim.x;
    for (int e = t; e < E; e += stride) {
        int s = ei[e], d = ei[E + e];
        const float* ys = y + (size_t)s * FF;
        float* zd = z + (size_t)d * FF;
#pragma unroll
        for (int f = 0; f < FF; f++) atomicAdd(&zd[f], ys[f]);
    }
}
__global__ void k_mid(const float* __restrict__ z1, const float* __restrict__ dis,
                      const float* __restrict__ b1, const float* __restrict__ W2,
                      float* __restrict__ y2, float* __restrict__ z2) {
    int i = blockIdx.x * blockDim.x + threadIdx.x;
    if (i >= NN) return;
    float d = dis[i];
    float h[FF];
#pragma unroll
    for (int f = 0; f < FF; f++) h[f] = fmaxf(z1[i * FF + f] * d + b1[f], 0.f);
#pragma unroll
    for (int o = 0; o < FF; o++) {
        float acc = 0.f;
#pragma unroll
        for (int k = 0; k < FF; k++) acc += h[k] * W2[k * FF + o];
        acc *= d;
        y2[i * FF + o] = acc;
        z2[i * FF + o] = acc;
    }
}
__global__ void k_final(const float* __restrict__ z2, const float* __restrict__ dis,
                        const float* __restrict__ b2, const float* __restrict__ Wl,
                        const float* __restrict__ bl, float* __restrict__ out) {
    int i = blockIdx.x * blockDim.x + threadIdx.x;
    if (i >= NN) return;
    float d = dis[i];
    float acc = bl[0];
#pragma unroll
    for (int f = 0; f < FF; f++)
        acc += fmaxf(z2[i * FF + f] * d + b2[f], 0.f) * Wl[f];
    out[i] = acc;
}

// ================================ launch ================================

extern "C" void kernel_launch(void* const* d_in, const int* in_sizes, int n_in,
                              void* d_out, int out_size, void* d_ws, size_t ws_size,
                              hipStream_t stream) {
    const float* x  = (const float*)d_in[0];
    const int*   ei = (const int*)d_in[1];
    const float* W1 = (const float*)d_in[2];
    const float* b1 = (const float*)d_in[3];
    const float* W2 = (const float*)d_in[4];
    const float* b2 = (const float*)d_in[5];
    const float* Wl = (const float*)d_in[6];
    const float* bl = (const float*)d_in[7];
    float* out = (float*)d_out;
    const int E = in_sizes[1] / 2;

    char* ws = (char*)d_ws;
    const size_t REQUIRED = 171ull << 20;

    if (E == EE && ws_size >= REQUIRED) {
        // layout: totals@0(4K), base@64K(4K), blockHist@128K(2MB),
        // dis@4M(4MB), y16@8M(16MB), y2@25M(16MB), binned@42M(128MB+pad)
        u32*   totals    = (u32*)(ws);
        u32*   base      = (u32*)(ws + (64 << 10));
        u32*   blockHist = (u32*)(ws + (128 << 10));
        float* dis       = (float*)(ws + (4ull << 20));
        uint4* y16       = (uint4*)(ws + (8ull << 20));
        uint4* y2        = (uint4*)(ws + (25ull << 20));
        u32*   binned    = (u32*)(ws + (42ull << 20));

        hipMemsetAsync(totals, 0, NBUCK * sizeof(u32), stream);

        k_hist   <<<NBLK, 1024, 0, stream>>>(ei, blockHist, totals);
        k_base   <<<1, 1024, 0, stream>>>(totals, base);
        k_off    <<<NBUCK, NBLK, 0, stream>>>(blockHist, base);
        k_scatter<<<NBLK, 1024, 0, stream>>>(ei, blockHist, binned);
        k_pad    <<<1, 1024, 0, stream>>>(totals, base, binned);
        k_disy   <<<NBUCK, 1024, 0, stream>>>(binned, base, totals, x, W1, dis, y16);
        k_agg1   <<<NBUCK, 1024, 0, stream>>>(binned, base, totals, y16, dis, b1, W2, y2);
        k_agg2   <<<NBUCK, 1024, 0, stream>>>(binned, base, totals, y2, dis, b2, Wl, bl, out);
    } else {
        // -------- fallback: round-1 global-atomic path (needs 68 MB) --------
        unsigned int* deg = (unsigned int*)(ws);
        float* dis = (float*)(ws + (size_t)4 * 1024 * 1024);
        float* A   = (float*)(ws + (size_t)8 * 1024 * 1024);
        float* B   = (float*)(ws + (size_t)28 * 1024 * 1024);
        float* C   = (float*)(ws + (size_t)48 * 1024 * 1024);

        hipMemsetAsync(deg, 0, (size_t)NN * sizeof(unsigned int), stream);

        const int ET = 256, EB = 2048;
        const int NT = 256, NB = (NN + NT - 1) / NT;
        k_deg  <<<EB, ET, 0, stream>>>(ei, E, deg);
        k_dis  <<<NB, NT, 0, stream>>>(deg, dis);
        k_y1   <<<NB, NT, 0, stream>>>(x, dis, W1, A, B);
        k_edge <<<EB, ET, 0, stream>>>(ei, E, A, B);
        k_mid  <<<NB, NT, 0, stream>>>(B, dis, b1, W2, A, C);
        k_edge <<<EB, ET, 0, stream>>>(ei, E, A, C);
        k_final<<<NB, NT, 0, stream>>>(C, dis, b2, Wl, bl, out);
    }
}

// Round 6
// 2103.326 us; speedup vs baseline: 1.2037x; 1.0322x over previous
//
#include <hip/hip_runtime.h>
#include <math.h>

#define NN 1000000
#define FF 5
#define EE 32000000
#define BBITS 10
#define BWIDTH 1024
#define NBUCK 977            /* ((NN-1)>>BBITS)+1 */
#define NBLK 512             /* edge-slice blocks for hist/scatter */
#define SLICE (EE / NBLK)    /* 62500 exactly */

typedef unsigned u32;
typedef u32 u32x4 __attribute__((ext_vector_type(4)));
typedef int i32x4 __attribute__((ext_vector_type(4)));

// ---- 16B row codec: 4 x f24 (rounded) + 1 x f32 exact ----
__device__ __forceinline__ u32 rnd24(float v) {
    return (__float_as_uint(v) + 0x80u) >> 8;
}
__device__ __forceinline__ uint4 pack_row(float o0, float o1, float o2, float o3, float o4) {
    u32 t0 = rnd24(o0), t1 = rnd24(o1), t2 = rnd24(o2), t3 = rnd24(o3);
    uint4 r;
    r.x = t0 | (t1 << 24);
    r.y = (t1 >> 8) | (t2 << 16);
    r.z = (t2 >> 16) | (t3 << 8);
    r.w = __float_as_uint(o4);
    return r;
}
__device__ __forceinline__ void unpack_row(uint4 r, float* f) {
    f[0] = __uint_as_float(r.x << 8);
    f[1] = __uint_as_float(((r.x >> 24) << 8) | (r.y << 16));
    f[2] = __uint_as_float(((r.y >> 16) << 8) | (r.z << 24));
    f[3] = __uint_as_float(r.z & 0xFFFFFF00u);
    f[4] = __uint_as_float(r.w);
}

// ======================= SHARED PREP (binning) =======================

__global__ __launch_bounds__(1024) void k_hist(const int* __restrict__ ei,
                                               u32* __restrict__ blockHist,
                                               u32* __restrict__ totals) {
    __shared__ u32 h[NBUCK];
    int t = threadIdx.x, blk = blockIdx.x;
    for (int i = t; i < NBUCK; i += 1024) h[i] = 0u;
    __syncthreads();
    const i32x4* dsts = (const i32x4*)(ei + EE + (size_t)blk * SLICE);
    for (int i = t; i < SLICE / 4; i += 1024) {
        i32x4 d = __builtin_nontemporal_load(dsts + i);
        atomicAdd(&h[((u32)d.x) >> BBITS], 1u);
        atomicAdd(&h[((u32)d.y) >> BBITS], 1u);
        atomicAdd(&h[((u32)d.z) >> BBITS], 1u);
        atomicAdd(&h[((u32)d.w) >> BBITS], 1u);
    }
    __syncthreads();
    for (int i = t; i < NBUCK; i += 1024) {
        u32 c = h[i];
        blockHist[(size_t)i * NBLK + blk] = c;
        if (c) atomicAdd(&totals[i], c);
    }
}

__global__ __launch_bounds__(1024) void k_base(const u32* __restrict__ totals,
                                               u32* __restrict__ base) {
    __shared__ u32 s[1024];
    int t = threadIdx.x;
    u32 v = (t < NBUCK) ? ((totals[t] + 7u) & ~7u) : 0u;
    s[t] = v;
    __syncthreads();
    for (int off = 1; off < 1024; off <<= 1) {
        u32 add = (t >= off) ? s[t - off] : 0u;
        __syncthreads();
        s[t] += add;
        __syncthreads();
    }
    if (t < NBUCK) base[t] = s[t] - v;
}

__global__ __launch_bounds__(NBLK) void k_off(u32* __restrict__ blockHist,
                                              const u32* __restrict__ base) {
    __shared__ u32 s[NBLK];
    size_t bb = (size_t)blockIdx.x * NBLK;
    int t = threadIdx.x;
    u32 v = blockHist[bb + t];
    s[t] = v;
    __syncthreads();
    for (int off = 1; off < NBLK; off <<= 1) {
        u32 a = (t >= off) ? s[t - off] : 0u;
        __syncthreads();
        s[t] += a;
        __syncthreads();
    }
    blockHist[bb + t] = base[blockIdx.x] + s[t] - v;
}

__global__ __launch_bounds__(1024) void k_scatter(const int* __restrict__ ei,
                                                  const u32* __restrict__ blockHist,
                                                  u32* __restrict__ binned) {
    __shared__ u32 cnt[NBUCK];
    int t = threadIdx.x, blk = blockIdx.x;
    for (int i = t; i < NBUCK; i += 1024)
        cnt[i] = blockHist[(size_t)i * NBLK + blk];
    __syncthreads();
    const i32x4* srcs = (const i32x4*)(ei + (size_t)blk * SLICE);
    const i32x4* dsts = (const i32x4*)(ei + EE + (size_t)blk * SLICE);
    for (int i = t; i < SLICE / 4; i += 1024) {
        i32x4 s4 = __builtin_nontemporal_load(srcs + i);
        i32x4 d4 = __builtin_nontemporal_load(dsts + i);
#pragma unroll
        for (int j = 0; j < 4; j++) {
            u32 s = (u32)((j == 0) ? s4.x : (j == 1) ? s4.y : (j == 2) ? s4.z : s4.w);
            u32 d = (u32)((j == 0) ? d4.x : (j == 1) ? d4.y : (j == 2) ? d4.z : d4.w);
            u32 pos = atomicAdd(&cnt[d >> BBITS], 1u);
            binned[pos] = (s << BBITS) | (d & (BWIDTH - 1));
        }
    }
}

__global__ __launch_bounds__(1024) void k_pad(const u32* __restrict__ totals,
                                              const u32* __restrict__ base,
                                              u32* __restrict__ binned) {
    int t = threadIdx.x;
    if (t >= NBUCK) return;
    u32 len = totals[t];
    u32 st = base[t] + len;
    u32 en = base[t] + ((len + 7u) & ~7u);
    for (u32 u = st; u < en; u++) binned[u] = ((u32)NN) << BBITS;
}

// ===================== NEW: full sort + register agg =====================

// Per bucket: count per-node (u32 LDS atomics) -> exclusive scan -> placement
// scatter to srcSorted (edges ordered by exact dst). Also emits deg, rowStart,
// dis, and packed y16 = pack((x@W1)*dis). Zero f32 atomics anywhere.
__global__ __launch_bounds__(1024) void k_sort(const u32* __restrict__ binned,
                                               const u32* __restrict__ base,
                                               const u32* __restrict__ totals,
                                               const float* __restrict__ x,
                                               const float* __restrict__ W,
                                               u32* __restrict__ srcSorted,
                                               u32* __restrict__ rowStart,
                                               u32* __restrict__ deg,
                                               float* __restrict__ dis,
                                               uint4* __restrict__ y16) {
    __shared__ u32 c[BWIDTH];
    __shared__ u32 o[BWIDTH];
    int t = threadIdx.x, b = blockIdx.x;
    c[t] = 0u;
    __syncthreads();
    u32 start = base[b], len = totals[b], lenp = (len + 7u) & ~7u;
    for (u32 i = (u32)t * 8u; i < lenp; i += 8192u) {
        const u32x4* bp = (const u32x4*)(binned + start + i);
        u32x4 a = __builtin_nontemporal_load(bp);
        u32x4 d2 = __builtin_nontemporal_load(bp + 1);
        u32 p[8] = {a.x, a.y, a.z, a.w, d2.x, d2.y, d2.z, d2.w};
#pragma unroll
        for (int j = 0; j < 8; j++)
            if ((p[j] >> BBITS) != (u32)NN)
                atomicAdd(&c[p[j] & (BWIDTH - 1)], 1u);
    }
    __syncthreads();
    u32 cnt = c[t];
    o[t] = cnt;                       // Hillis-Steele inclusive scan
    __syncthreads();
    for (int off = 1; off < BWIDTH; off <<= 1) {
        u32 add = (t >= off) ? o[t - off] : 0u;
        __syncthreads();
        o[t] += add;
        __syncthreads();
    }
    u32 myStart = o[t] - cnt;         // exclusive
    int node = (b << BBITS) + t;
    if (node < NN) { deg[node] = cnt; rowStart[node] = start + myStart; }
    c[t] = myStart;                   // running placement counters
    __syncthreads();
    for (u32 i = (u32)t * 8u; i < lenp; i += 8192u) {
        const u32x4* bp = (const u32x4*)(binned + start + i);
        u32x4 a = __builtin_nontemporal_load(bp);
        u32x4 d2 = __builtin_nontemporal_load(bp + 1);
        u32 p[8] = {a.x, a.y, a.z, a.w, d2.x, d2.y, d2.z, d2.w};
#pragma unroll
        for (int j = 0; j < 8; j++) {
            u32 pj = p[j];
            if ((pj >> BBITS) != (u32)NN) {
                u32 pos = atomicAdd(&c[pj & (BWIDTH - 1)], 1u);
                srcSorted[start + pos] = pj >> BBITS;
            }
        }
    }
    if (node >= NN) return;
    float d = rsqrtf((float)(cnt + 1u));
    dis[node] = d;
    float xi[FF];
#pragma unroll
    for (int f = 0; f < FF; f++) xi[f] = x[(size_t)node * FF + f];
    float ov[FF];
#pragma unroll
    for (int q = 0; q < FF; q++) {
        float acc = 0.f;
#pragma unroll
        for (int k = 0; k < FF; k++) acc += xi[k] * W[k * FF + q];
        ov[q] = acc * d;
    }
    y16[node] = pack_row(ov[0], ov[1], ov[2], ov[3], ov[4]);
}

// layer-1: thread-per-node register aggregation + fused epilogue -> packed y2.
__global__ __launch_bounds__(1024) void k_rag1(const u32* __restrict__ srcSorted,
                                               const u32* __restrict__ rowStart,
                                               const u32* __restrict__ deg,
                                               const uint4* __restrict__ y16,
                                               const float* __restrict__ dis,
                                               const float* __restrict__ b1,
                                               const float* __restrict__ W2,
                                               uint4* __restrict__ y2) {
    int node = blockIdx.x * 1024 + threadIdx.x;
    if (node >= NN) return;
    u32 st = rowStart[node], n = deg[node];
    float a[FF] = {0.f, 0.f, 0.f, 0.f, 0.f};
    u32 k = 0;
    for (; k + 4 <= n; k += 4) {        // 4 independent gathers in flight
        u32 s0 = srcSorted[st + k + 0];
        u32 s1 = srcSorted[st + k + 1];
        u32 s2 = srcSorted[st + k + 2];
        u32 s3 = srcSorted[st + k + 3];
        uint4 r0 = y16[s0], r1 = y16[s1], r2 = y16[s2], r3 = y16[s3];
        float f0[FF], f1[FF], f2[FF], f3[FF];
        unpack_row(r0, f0); unpack_row(r1, f1);
        unpack_row(r2, f2); unpack_row(r3, f3);
#pragma unroll
        for (int f = 0; f < FF; f++) a[f] += (f0[f] + f1[f]) + (f2[f] + f3[f]);
    }
    for (; k < n; ++k) {
        uint4 r = y16[srcSorted[st + k]];
        float fv[FF];
        unpack_row(r, fv);
#pragma unroll
        for (int f = 0; f < FF; f++) a[f] += fv[f];
    }
    float selfv[FF];
    unpack_row(y16[node], selfv);
    float d = dis[node];
    float h[FF];
#pragma unroll
    for (int f = 0; f < FF; f++)
        h[f] = fmaxf((a[f] + selfv[f]) * d + b1[f], 0.f);
    float ov[FF];
#pragma unroll
    for (int q = 0; q < FF; q++) {
        float s = 0.f;
#pragma unroll
        for (int kk = 0; kk < FF; kk++) s += h[kk] * W2[kk * FF + q];
        ov[q] = s * d;
    }
    y2[node] = pack_row(ov[0], ov[1], ov[2], ov[3], ov[4]);
}

// layer-2: register aggregation + fused head -> out.
__global__ __launch_bounds__(1024) void k_rag2(const u32* __restrict__ srcSorted,
                                               const u32* __restrict__ rowStart,
                                               const u32* __restrict__ deg,
                                               const uint4* __restrict__ y2,
                                               const float* __restrict__ dis,
                                               const float* __restrict__ b2,
                                               const float* __restrict__ Wl,
                                               const float* __restrict__ bl,
                                               float* __restrict__ out) {
    int node = blockIdx.x * 1024 + threadIdx.x;
    if (node >= NN) return;
    u32 st = rowStart[node], n = deg[node];
    float a[FF] = {0.f, 0.f, 0.f, 0.f, 0.f};
    u32 k = 0;
    for (; k + 4 <= n; k += 4) {
        u32 s0 = srcSorted[st + k + 0];
        u32 s1 = srcSorted[st + k + 1];
        u32 s2 = srcSorted[st + k + 2];
        u32 s3 = srcSorted[st + k + 3];
        uint4 r0 = y2[s0], r1 = y2[s1], r2 = y2[s2], r3 = y2[s3];
        float f0[FF], f1[FF], f2[FF], f3[FF];
        unpack_row(r0, f0); unpack_row(r1, f1);
        unpack_row(r2, f2); unpack_row(r3, f3);
#pragma unroll
        for (int f = 0; f < FF; f++) a[f] += (f0[f] + f1[f]) + (f2[f] + f3[f]);
    }
    for (; k < n; ++k) {
        uint4 r = y2[srcSorted[st + k]];
        float fv[FF];
        unpack_row(r, fv);
#pragma unroll
        for (int f = 0; f < FF; f++) a[f] += fv[f];
    }
    float selfv[FF];
    unpack_row(y2[node], selfv);
    float d = dis[node];
    float v = bl[0];
#pragma unroll
    for (int f = 0; f < FF; f++)
        v += fmaxf((a[f] + selfv[f]) * d + b2[f], 0.f) * Wl[f];
    out[node] = v;
}

// ============== MID FALLBACK (round-5 LDS-atomic path) ==============

__global__ __launch_bounds__(1024) void k_disy(const u32* __restrict__ binned,
                                               const u32* __restrict__ base,
                                               const u32* __restrict__ totals,
                                               const float* __restrict__ x,
                                               const float* __restrict__ W,
                                               float* __restrict__ dis,
                                               uint4* __restrict__ y16) {
    __shared__ u32 c[BWIDTH];
    int t = threadIdx.x, b = blockIdx.x;
    c[t] = 0u;
    __syncthreads();
    u32 start = base[b], len = totals[b], lenp = (len + 7u) & ~7u;
    for (u32 i = (u32)t * 8u; i < lenp; i += 8192u) {
        const u32x4* bp = (const u32x4*)(binned + start + i);
        u32x4 a = __builtin_nontemporal_load(bp);
        u32x4 d = __builtin_nontemporal_load(bp + 1);
        u32 p[8] = {a.x, a.y, a.z, a.w, d.x, d.y, d.z, d.w};
#pragma unroll
        for (int j = 0; j < 8; j++)
            if ((p[j] >> BBITS) != (u32)NN)
                atomicAdd(&c[p[j] & (BWIDTH - 1)], 1u);
    }
    __syncthreads();
    int node = (b << BBITS) + t;
    if (node > NN) return;
    if (node == NN) { y16[node] = make_uint4(0u, 0u, 0u, 0u); return; }
    float d = rsqrtf((float)(c[t] + 1u));
    dis[node] = d;
    float xi[FF];
#pragma unroll
    for (int f = 0; f < FF; f++) xi[f] = x[(size_t)node * FF + f];
    float o[FF];
#pragma unroll
    for (int q = 0; q < FF; q++) {
        float acc = 0.f;
#pragma unroll
        for (int k = 0; k < FF; k++) acc += xi[k] * W[k * FF + q];
        o[q] = acc * d;
    }
    y16[node] = pack_row(o[0], o[1], o[2], o[3], o[4]);
}

__global__ __launch_bounds__(1024) void k_agg1(const u32* __restrict__ binned,
                                               const u32* __restrict__ base,
                                               const u32* __restrict__ totals,
                                               const uint4* __restrict__ y16,
                                               const float* __restrict__ dis,
                                               const float* __restrict__ b1,
                                               const float* __restrict__ W2,
                                               uint4* __restrict__ y2) {
    __shared__ float acc[BWIDTH * FF];
    int t = threadIdx.x, b = blockIdx.x;
#pragma unroll
    for (int i = 0; i < FF; i++) acc[i * 1024 + t] = 0.f;
    __syncthreads();
    u32 start = base[b], len = totals[b], lenp = (len + 7u) & ~7u;
    for (u32 i = (u32)t * 8u; i < lenp; i += 8192u) {
        const u32x4* bp = (const u32x4*)(binned + start + i);
        u32x4 qa = __builtin_nontemporal_load(bp);
        u32x4 qb = __builtin_nontemporal_load(bp + 1);
        u32 p[8] = {qa.x, qa.y, qa.z, qa.w, qb.x, qb.y, qb.z, qb.w};
        uint4 r[8];
#pragma unroll
        for (int j = 0; j < 8; j++) r[j] = y16[p[j] >> BBITS];
#pragma unroll
        for (int j = 0; j < 8; j++) {
            float f[FF];
            unpack_row(r[j], f);
            float* a = acc + (p[j] & (BWIDTH - 1)) * FF;
            atomicAdd(a + 0, f[0]); atomicAdd(a + 1, f[1]); atomicAdd(a + 2, f[2]);
            atomicAdd(a + 3, f[3]); atomicAdd(a + 4, f[4]);
        }
    }
    __syncthreads();
    int node = (b << BBITS) + t;
    if (node > NN) return;
    if (node == NN) { y2[node] = make_uint4(0u, 0u, 0u, 0u); return; }
    float self[FF];
    unpack_row(y16[node], self);
    float d = dis[node];
    float h[FF];
#pragma unroll
    for (int f = 0; f < FF; f++)
        h[f] = fmaxf((acc[t * FF + f] + self[f]) * d + b1[f], 0.f);
    float o[FF];
#pragma unroll
    for (int q = 0; q < FF; q++) {
        float s = 0.f;
#pragma unroll
        for (int k = 0; k < FF; k++) s += h[k] * W2[k * FF + q];
        o[q] = s * d;
    }
    y2[node] = pack_row(o[0], o[1], o[2], o[3], o[4]);
}

__global__ __launch_bounds__(1024) void k_agg2(const u32* __restrict__ binned,
                                               const u32* __restrict__ base,
                                               const u32* __restrict__ totals,
                                               const uint4* __restrict__ y2,
                                               const float* __restrict__ dis,
                                               const float* __restrict__ b2,
                                               const float* __restrict__ Wl,
                                               const float* __restrict__ bl,
                                               float* __restrict__ out) {
    __shared__ float acc[BWIDTH * FF];
    int t = threadIdx.x, b = blockIdx.x;
#pragma unroll
    for (int i = 0; i < FF; i++) acc[i * 1024 + t] = 0.f;
    __syncthreads();
    u32 start = base[b], len = totals[b], lenp = (len + 7u) & ~7u;
    for (u32 i = (u32)t * 8u; i < lenp; i += 8192u) {
        const u32x4* bp = (const u32x4*)(binned + start + i);
        u32x4 qa = __builtin_nontemporal_load(bp);
        u32x4 qb = __builtin_nontemporal_load(bp + 1);
        u32 p[8] = {qa.x, qa.y, qa.z, qa.w, qb.x, qb.y, qb.z, qb.w};
        uint4 r[8];
#pragma unroll
        for (int j = 0; j < 8; j++) r[j] = y2[p[j] >> BBITS];
#pragma unroll
        for (int j = 0; j < 8; j++) {
            float f[FF];
            unpack_row(r[j], f);
            float* a = acc + (p[j] & (BWIDTH - 1)) * FF;
            atomicAdd(a + 0, f[0]); atomicAdd(a + 1, f[1]); atomicAdd(a + 2, f[2]);
            atomicAdd(a + 3, f[3]); atomicAdd(a + 4, f[4]);
        }
    }
    __syncthreads();
    int node = (b << BBITS) + t;
    if (node >= NN) return;
    float self[FF];
    unpack_row(y2[node], self);
    float d = dis[node];
    float v = bl[0];
#pragma unroll
    for (int f = 0; f < FF; f++)
        v += fmaxf((acc[t * FF + f] + self[f]) * d + b2[f], 0.f) * Wl[f];
    out[node] = v;
}

// ============== FAR FALLBACK (round-1 global-atomic path) ==============

__global__ void k_deg(const int* __restrict__ ei, int E, unsigned int* __restrict__ dg) {
    int t = blockIdx.x * blockDim.x + threadIdx.x;
    int stride = gridDim.x * blockDim.x;
    for (int e = t; e < E; e += stride) atomicAdd(&dg[ei[E + e]], 1u);
}
__global__ void k_dis(const unsigned int* __restrict__ dg, float* __restrict__ dis) {
    int i = blockIdx.x * blockDim.x + threadIdx.x;
    if (i < NN) dis[i] = rsqrtf((float)(dg[i] + 1u));
}
__global__ void k_y1(const float* __restrict__ x, const float* __restrict__ dis,
                     const float* __restrict__ W, float* __restrict__ y, float* __restrict__ z) {
    int i = blockIdx.x * blockDim.x + threadIdx.x;
    if (i >= NN) return;
    float xi[FF];
#pragma unroll
    for (int f = 0; f < FF; f++) xi[f] = x[i * FF + f];
    float d = dis[i];
#pragma unroll
    for (int o = 0; o < FF; o++) {
        float acc = 0.f;
#pragma unroll
        for (int k = 0; k < FF; k++) acc += xi[k] * W[k * FF + o];
        acc *= d;
        y[i * FF + o] = acc;
        z[i * FF + o] = acc;
    }
}
__global__ void k_edge(const int* __restrict__ ei, int E,
                       const float* __restrict__ y, float* __restrict__ z) {
    int t = blockIdx.x * blockDim.x + threadIdx.x;
    int stride = gridDim.x * blockDim.x;
    for (int e = t; e < E; e += stride) {
        int s = ei[e], d = ei[E + e];
        const float* ys = y + (size_t)s * FF;
        float* zd = z + (size_t)d * FF;
#pragma unroll
        for (int f = 0; f < FF; f++) atomicAdd(&zd[f], ys[f]);
    }
}
__global__ void k_mid(const float* __restrict__ z1, const float* __restrict__ dis,
                      const float* __restrict__ b1, const float* __restrict__ W2,
                      float* __restrict__ y2, float* __restrict__ z2) {
    int i = blockIdx.x * blockDim.x + threadIdx.x;
    if (i >= NN) return;
    float d = dis[i];
    float h[FF];
#pragma unroll
    for (int f = 0; f < FF; f++) h[f] = fmaxf(z1[i * FF + f] * d + b1[f], 0.f);
#pragma unroll
    for (int o = 0; o < FF; o++) {
        float acc = 0.f;
#pragma unroll
        for (int k = 0; k < FF; k++) acc += h[k] * W2[k * FF + o];
        acc *= d;
        y2[i * FF + o] = acc;
        z2[i * FF + o] = acc;
    }
}
__global__ void k_final(const float* __restrict__ z2, const float* __restrict__ dis,
                        const float* __restrict__ b2, const float* __restrict__ Wl,
                        const float* __restrict__ bl, float* __restrict__ out) {
    int i = blockIdx.x * blockDim.x + threadIdx.x;
    if (i >= NN) return;
    float d = dis[i];
    float acc = bl[0];
#pragma unroll
    for (int f = 0; f < FF; f++)
        acc += fmaxf(z2[i * FF + f] * d + b2[f], 0.f) * Wl[f];
    out[i] = acc;
}

// ================================ launch ================================

extern "C" void kernel_launch(void* const* d_in, const int* in_sizes, int n_in,
                              void* d_out, int out_size, void* d_ws, size_t ws_size,
                              hipStream_t stream) {
    const float* x  = (const float*)d_in[0];
    const int*   ei = (const int*)d_in[1];
    const float* W1 = (const float*)d_in[2];
    const float* b1 = (const float*)d_in[3];
    const float* W2 = (const float*)d_in[4];
    const float* b2 = (const float*)d_in[5];
    const float* Wl = (const float*)d_in[6];
    const float* bl = (const float*)d_in[7];
    float* out = (float*)d_out;
    const int E = in_sizes[1] / 2;

    char* ws = (char*)d_ws;
    const size_t REQ_SORT = 294ull << 20;   // full-sort register-agg path
    const size_t REQ_MID  = 171ull << 20;   // round-5 LDS-atomic path

    if (E == EE && ws_size >= REQ_SORT) {
        // totals@0, base@64K, blockHist@128K(2MB), dis@4M, deg@8M, rowStart@12M,
        // y16@16M(16MB), y2@32M(16MB), binned@48M(122.1MB), srcSorted@171M(122.1MB)
        u32*   totals    = (u32*)(ws);
        u32*   base      = (u32*)(ws + (64 << 10));
        u32*   blockHist = (u32*)(ws + (128 << 10));
        float* dis       = (float*)(ws + (4ull << 20));
        u32*   deg       = (u32*)(ws + (8ull << 20));
        u32*   rowStart  = (u32*)(ws + (12ull << 20));
        uint4* y16       = (uint4*)(ws + (16ull << 20));
        uint4* y2        = (uint4*)(ws + (32ull << 20));
        u32*   binned    = (u32*)(ws + (48ull << 20));
        u32*   srcSorted = (u32*)(ws + (171ull << 20));

        hipMemsetAsync(totals, 0, NBUCK * sizeof(u32), stream);

        k_hist   <<<NBLK, 1024, 0, stream>>>(ei, blockHist, totals);
        k_base   <<<1, 1024, 0, stream>>>(totals, base);
        k_off    <<<NBUCK, NBLK, 0, stream>>>(blockHist, base);
        k_scatter<<<NBLK, 1024, 0, stream>>>(ei, blockHist, binned);
        k_pad    <<<1, 1024, 0, stream>>>(totals, base, binned);
        k_sort   <<<NBUCK, 1024, 0, stream>>>(binned, base, totals, x, W1,
                                              srcSorted, rowStart, deg, dis, y16);
        k_rag1   <<<NBUCK, 1024, 0, stream>>>(srcSorted, rowStart, deg, y16, dis, b1, W2, y2);
        k_rag2   <<<NBUCK, 1024, 0, stream>>>(srcSorted, rowStart, deg, y2, dis, b2, Wl, bl, out);
    } else if (E == EE && ws_size >= REQ_MID) {
        u32*   totals    = (u32*)(ws);
        u32*   base      = (u32*)(ws + (64 << 10));
        u32*   blockHist = (u32*)(ws + (128 << 10));
        float* dis       = (float*)(ws + (4ull << 20));
        uint4* y16       = (uint4*)(ws + (8ull << 20));
        uint4* y2        = (uint4*)(ws + (25ull << 20));
        u32*   binned    = (u32*)(ws + (42ull << 20));

        hipMemsetAsync(totals, 0, NBUCK * sizeof(u32), stream);

        k_hist   <<<NBLK, 1024, 0, stream>>>(ei, blockHist, totals);
        k_base   <<<1, 1024, 0, stream>>>(totals, base);
        k_off    <<<NBUCK, NBLK, 0, stream>>>(blockHist, base);
        k_scatter<<<NBLK, 1024, 0, stream>>>(ei, blockHist, binned);
        k_pad    <<<1, 1024, 0, stream>>>(totals, base, binned);
        k_disy   <<<NBUCK, 1024, 0, stream>>>(binned, base, totals, x, W1, dis, y16);
        k_agg1   <<<NBUCK, 1024, 0, stream>>>(binned, base, totals, y16, dis, b1, W2, y2);
        k_agg2   <<<NBUCK, 1024, 0, stream>>>(binned, base, totals, y2, dis, b2, Wl, bl, out);
    } else {
        unsigned int* dg = (unsigned int*)(ws);
        float* dis = (float*)(ws + (size_t)4 * 1024 * 1024);
        float* A   = (float*)(ws + (size_t)8 * 1024 * 1024);
        float* B   = (float*)(ws + (size_t)28 * 1024 * 1024);
        float* C   = (float*)(ws + (size_t)48 * 1024 * 1024);

        hipMemsetAsync(dg, 0, (size_t)NN * sizeof(unsigned int), stream);

        const int ET = 256, EB = 2048;
        const int NT = 256, NB = (NN + NT - 1) / NT;
        k_deg  <<<EB, ET, 0, stream>>>(ei, E, dg);
        k_dis  <<<NB, NT, 0, stream>>>(dg, dis);
        k_y1   <<<NB, NT, 0, stream>>>(x, dis, W1, A, B);
        k_edge <<<EB, ET, 0, stream>>>(ei, E, A, B);
        k_mid  <<<NB, NT, 0, stream>>>(B, dis, b1, W2, A, C);
        k_edge <<<EB, ET, 0, stream>>>(ei, E, A, C);
        k_final<<<NB, NT, 0, stream>>>(C, dis, b2, Wl, bl, out);
    }
}